// Round 3
// baseline (754.830 us; speedup 1.0000x reference)
//
#include <hip/hip_runtime.h>

#define N_NODES 100000
#define N_EDGES 1600000
#define IN_DIM 160
#define HID 128
#define BN_EPS 1e-5f

#define M_PAD 100096   // 782 * 128 rows (GEMM block = 128 rows)
#define NBUCK 196      // 512-node buckets (196*512 = 100352 >= N_NODES)
#define BSH 9
#define EPB 8192       // edges per block in hist/scatter kernels
#define NHB (NBUCK * NBUCK)
#define K2CHUNK 152    // 256*152 = 38912 >= NHB
#define NPN 4          // nodes per wave in agg kernel

typedef unsigned int uint;
typedef unsigned short ushort;
typedef __attribute__((ext_vector_type(8))) short bf16x8;
typedef __attribute__((ext_vector_type(4))) float f32x4;

__device__ __forceinline__ ushort bf16rn(float f) {
    uint u = __float_as_uint(f);
    u += 0x7fffu + ((u >> 16) & 1u);
    return (ushort)(u >> 16);
}

// ---------------------------------------------------------------------------
// CSR build via two-level bucket sort (no global atomic scatter churn).
// k1: per-block histogram over 196 buckets -> ghist[bucket][block]
// k2: exclusive scan of ghist (bucket-major) + bucket bases gbb[197]
// k3: scatter edges into bucket-grouped scat[] (block-private runs)
// k4: per-bucket local CSR: counts, prefix, rowptr, eidx (block-private)
// ---------------------------------------------------------------------------

__global__ __launch_bounds__(256) void hist_kernel(const int* __restrict__ dst,
                                                   int* __restrict__ ghist) {
    __shared__ int hist[NBUCK];
    int b = blockIdx.x, t = threadIdx.x;
    for (int i = t; i < NBUCK; i += 256) hist[i] = 0;
    __syncthreads();
    int e0 = b * EPB;
    for (int i = 0; i < EPB; i += 256) {
        int e = e0 + i + t;
        if (e < N_EDGES) atomicAdd(&hist[dst[e] >> BSH], 1);
    }
    __syncthreads();
    for (int i = t; i < NBUCK; i += 256) ghist[i * NBUCK + b] = hist[i];
}

// Single block: exclusive scan of NHB ints in-place; per-thread serial chunks
// + LDS scan of 256 thread totals. Also emits bucket bases.
__global__ __launch_bounds__(256) void scan_hist_kernel(int* __restrict__ ghist,
                                                        int* __restrict__ gbb) {
    __shared__ int tsum[256];
    int t = threadIdx.x;
    int base = t * K2CHUNK;
    int s = 0;
    for (int i = 0; i < K2CHUNK; ++i) {
        int idx = base + i;
        if (idx < NHB) s += ghist[idx];
    }
    tsum[t] = s;
    __syncthreads();
    for (int off = 1; off < 256; off <<= 1) {
        int v = (t >= off) ? tsum[t - off] : 0;
        __syncthreads();
        tsum[t] += v;
        __syncthreads();
    }
    int excl = (t > 0) ? tsum[t - 1] : 0;
    for (int i = 0; i < K2CHUNK; ++i) {
        int idx = base + i;
        if (idx < NHB) {
            int v = ghist[idx];
            ghist[idx] = excl;
            if ((idx % NBUCK) == 0) gbb[idx / NBUCK] = excl;
            excl += v;
        }
    }
    if (t == 0) gbb[NBUCK] = N_EDGES;
}

// Scatter (src, dst&511) packed words into bucket-grouped runs. Each block's
// run positions are deterministic (ghist scan), writes are block-private.
__global__ __launch_bounds__(256) void scatter_kernel(const int* __restrict__ src,
                                                      const int* __restrict__ dst,
                                                      const int* __restrict__ ghist,
                                                      uint* __restrict__ scat) {
    __shared__ int base[NBUCK];
    __shared__ int fill[NBUCK];
    int b = blockIdx.x, t = threadIdx.x;
    for (int i = t; i < NBUCK; i += 256) { base[i] = ghist[i * NBUCK + b]; fill[i] = 0; }
    __syncthreads();
    int e0 = b * EPB;
    for (int i = 0; i < EPB; i += 256) {
        int e = e0 + i + t;
        if (e < N_EDGES) {
            int d = dst[e];
            int sv = src[e];
            int bk = d >> BSH;
            int lp = atomicAdd(&fill[bk], 1);
            scat[base[bk] + lp] = (uint)sv | ((uint)(d & 511) << 17);
        }
    }
}

// One block per bucket: per-node counts in LDS, scan 512, write rowptr + eidx.
__global__ __launch_bounds__(256) void bucket_csr_kernel(const uint* __restrict__ scat,
                                                         const int* __restrict__ gbb,
                                                         int* __restrict__ rowptr,
                                                         int* __restrict__ eidx) {
    __shared__ int cnt[512], fl[512], pref[512];
    __shared__ int ts[256];
    int b = blockIdx.x, t = threadIdx.x;
    int beg = gbb[b], end = gbb[b + 1];
    cnt[t] = 0; cnt[t + 256] = 0;
    __syncthreads();
    for (int i = beg + t; i < end; i += 256)
        atomicAdd(&cnt[scat[i] >> 17], 1);
    __syncthreads();
    int c0 = cnt[2 * t], c1 = cnt[2 * t + 1];
    ts[t] = c0 + c1;
    __syncthreads();
    for (int off = 1; off < 256; off <<= 1) {
        int v = (t >= off) ? ts[t - off] : 0;
        __syncthreads();
        ts[t] += v;
        __syncthreads();
    }
    int ex = (t > 0) ? ts[t - 1] : 0;
    pref[2 * t] = ex;
    pref[2 * t + 1] = ex + c0;
    fl[t] = 0; fl[t + 256] = 0;
    int g0 = b * 512 + 2 * t;
    if (g0 <= N_NODES) rowptr[g0] = beg + ex;
    if (g0 + 1 <= N_NODES) rowptr[g0 + 1] = beg + ex + c0;
    __syncthreads();
    for (int i = beg + t; i < end; i += 256) {
        uint w = scat[i];
        int nl = (int)(w >> 17);
        int lp = atomicAdd(&fl[nl], 1);
        eidx[beg + pref[nl] + lp] = (int)(w & 0x1FFFFu);
    }
}

// ---------------------------------------------------------------------------
// Prep: weights -> Bt[256][K] bf16; BN -> scale/shift with bl folded in.
// ---------------------------------------------------------------------------
__global__ void prep_weights_kernel(const float* __restrict__ wl, const float* __restrict__ wr,
                                    ushort* __restrict__ Bt, int K) {
    int n = blockIdx.y;
    int k = blockIdx.x * 64 + threadIdx.x;
    if (k < K) {
        float v = (n < HID) ? wl[k * HID + n] : wr[k * HID + (n - HID)];
        Bt[n * K + k] = bf16rn(v);
    }
}

__global__ void bn_prep_kernel(const float* __restrict__ bl, const float* __restrict__ g,
                               const float* __restrict__ be, const float* __restrict__ rm,
                               const float* __restrict__ rv, float* __restrict__ scale,
                               float* __restrict__ shift) {
    int j = threadIdx.x;
    float s = g[j] * rsqrtf(rv[j] + BN_EPS);
    scale[j] = s;
    shift[j] = (bl[j] - rm[j]) * s + be[j];
}

// ---------------------------------------------------------------------------
// GEMM: t = A @ [wl | wr] -> tbuf [M_PAD][256] bf16 (cols 0..127 = wl part,
// 128..255 = wr/root part). Epilogue repacks C tiles through LDS so global
// stores are fully-coalesced 512B rows.
// ---------------------------------------------------------------------------
template <int K, bool AFP32>
__global__ __launch_bounds__(256) void gemm_kernel(const void* __restrict__ A_,
                                                   const ushort* __restrict__ Bt,
                                                   ushort* __restrict__ tbuf) {
    __shared__ ushort lds[4][16][256];  // 32 KB: per-wave 16x256 repack slice
    const int lane = threadIdx.x & 63;
    const int wv = threadIdx.x >> 6;
    const int col = lane & 15;
    const int kq = (lane >> 4) * 8;
    const int m0 = blockIdx.x * 128 + wv * 32 + col;
    f32x4 acc[2][16];
#pragma unroll
    for (int a = 0; a < 2; ++a)
#pragma unroll
        for (int t = 0; t < 16; ++t) acc[a][t] = (f32x4){0.f, 0.f, 0.f, 0.f};

#pragma unroll
    for (int k0 = 0; k0 < K; k0 += 32) {
        int kk = k0 + kq;
        bf16x8 a0, a1;
        if (AFP32) {
            const float* A = (const float*)A_;
            float4 z = make_float4(0.f, 0.f, 0.f, 0.f);
            float4 f00 = z, f01 = z, f10 = z, f11 = z;
            if (m0 < N_NODES) {
                f00 = *(const float4*)(A + (size_t)m0 * K + kk);
                f01 = *(const float4*)(A + (size_t)m0 * K + kk + 4);
            }
            if (m0 + 16 < N_NODES) {
                f10 = *(const float4*)(A + (size_t)(m0 + 16) * K + kk);
                f11 = *(const float4*)(A + (size_t)(m0 + 16) * K + kk + 4);
            }
            a0[0] = (short)bf16rn(f00.x); a0[1] = (short)bf16rn(f00.y);
            a0[2] = (short)bf16rn(f00.z); a0[3] = (short)bf16rn(f00.w);
            a0[4] = (short)bf16rn(f01.x); a0[5] = (short)bf16rn(f01.y);
            a0[6] = (short)bf16rn(f01.z); a0[7] = (short)bf16rn(f01.w);
            a1[0] = (short)bf16rn(f10.x); a1[1] = (short)bf16rn(f10.y);
            a1[2] = (short)bf16rn(f10.z); a1[3] = (short)bf16rn(f10.w);
            a1[4] = (short)bf16rn(f11.x); a1[5] = (short)bf16rn(f11.y);
            a1[6] = (short)bf16rn(f11.z); a1[7] = (short)bf16rn(f11.w);
        } else {
            const ushort* A = (const ushort*)A_;
            a0 = *(const bf16x8*)(A + (size_t)m0 * K + kk);
            a1 = *(const bf16x8*)(A + (size_t)(m0 + 16) * K + kk);
        }
#pragma unroll
        for (int t = 0; t < 16; ++t) {
            bf16x8 bfr = *(const bf16x8*)(Bt + (size_t)(t * 16 + col) * K + kk);
            acc[0][t] = __builtin_amdgcn_mfma_f32_16x16x32_bf16(a0, bfr, acc[0][t], 0, 0, 0);
            acc[1][t] = __builtin_amdgcn_mfma_f32_16x16x32_bf16(a1, bfr, acc[1][t], 0, 0, 0);
        }
    }

    // Epilogue: C/D layout col=lane&15, row=quad*4+reg. Repack 16x256 chunk
    // through this wave's LDS slice, then store coalesced 512B rows.
    const int quad = lane >> 4;
#pragma unroll
    for (int mt = 0; mt < 2; ++mt) {
#pragma unroll
        for (int tt = 0; tt < 16; ++tt)
#pragma unroll
            for (int r = 0; r < 4; ++r)
                lds[wv][quad * 4 + r][tt * 16 + col] = bf16rn(acc[mt][tt][r]);
        int mbase = blockIdx.x * 128 + wv * 32 + mt * 16;
#pragma unroll
        for (int i = 0; i < 8; ++i) {
            int lin = i * 64 + lane;
            int row = lin >> 5;   // 2 rows per 64-lane inst
            int cb = lin & 31;    // 8-ushort group within row
            bf16x8 v = *(const bf16x8*)&lds[wv][row][cb * 8];
            *(bf16x8*)(tbuf + (size_t)(mbase + row) * 256 + cb * 8) = v;
        }
    }
}

// ---------------------------------------------------------------------------
// Aggregation + BN + ReLU (+ fused final linear). One wave per NPN nodes;
// lane covers feature pair (2L, 2L+1) of the wl-part; root part read from
// tbuf cols 128..255 (bf16 pair per lane).
// ---------------------------------------------------------------------------
template <bool FINAL>
__global__ __launch_bounds__(256) void agg_kernel(
    const ushort* __restrict__ tbuf_,
    const int* __restrict__ rowptr, const int* __restrict__ eidx,
    const float* __restrict__ bnscale, const float* __restrict__ bnshift,
    const float* __restrict__ linw, const float* __restrict__ linb,
    ushort* __restrict__ hout, float* __restrict__ out) {
    const uint* tb = (const uint*)tbuf_;  // row = 128 uints (256 bf16)
    const int lane = threadIdx.x & 63;
    const int wv = (blockIdx.x * 256 + (int)threadIdx.x) >> 6;
    float2 sc = *(const float2*)(bnscale + 2 * lane);
    float2 sh = *(const float2*)(bnshift + 2 * lane);
    float w0 = 0.f, w1 = 0.f, lb = 0.f;
    if (FINAL) {
        float2 wvv = *(const float2*)(linw + 2 * lane);
        w0 = wvv.x; w1 = wvv.y; lb = linb[0];
    }
    const int n0 = wv * NPN;
    for (int i = 0; i < NPN; ++i) {
        int n = n0 + i;
        if (n >= N_NODES) return;
        int beg = __builtin_amdgcn_readfirstlane(rowptr[n]);
        int end = __builtin_amdgcn_readfirstlane(rowptr[n + 1]);
        float s0 = 0.f, s1 = 0.f;
        for (int e = beg; e < end; e += 8) {
            int c = end - e;
            uint u[8];
#pragma unroll
            for (int j = 0; j < 8; ++j) {
                int ee = (j < c) ? (e + j) : beg;
                int s = eidx[ee];
                u[j] = tb[(size_t)s * 128 + lane];
            }
#pragma unroll
            for (int j = 0; j < 8; ++j) {
                float f0 = __uint_as_float(u[j] << 16);
                float f1 = __uint_as_float(u[j] & 0xffff0000u);
                if (j < c) { s0 += f0; s1 += f1; }
            }
        }
        int deg = end - beg;
        float inv = 1.0f / (float)max(deg, 1);
        uint ur = tb[(size_t)n * 128 + 64 + lane];   // root part cols 128..255
        float r0 = __uint_as_float(ur << 16);
        float r1 = __uint_as_float(ur & 0xffff0000u);
        float o0 = fmaxf((s0 * inv + r0) * sc.x + sh.x, 0.f);
        float o1 = fmaxf((s1 * inv + r1) * sc.y + sh.y, 0.f);
        if (FINAL) {
            float p = o0 * w0 + o1 * w1;
#pragma unroll
            for (int off = 32; off; off >>= 1) p += __shfl_down(p, off);
            if (lane == 0) out[n] = p + lb;
        } else {
            uint pack = (uint)bf16rn(o0) | ((uint)bf16rn(o1) << 16);
            ((uint*)hout)[(size_t)n * 64 + lane] = pack;
        }
    }
}

// ---------------------------------------------------------------------------

extern "C" void kernel_launch(void* const* d_in, const int* in_sizes, int n_in,
                              void* d_out, int out_size, void* d_ws, size_t ws_size,
                              hipStream_t stream) {
    const float* x    = (const float*)d_in[0];
    const int*   ei   = (const int*)d_in[1];
    const int*   esrc = ei;
    const int*   edst = ei + N_EDGES;
    const float* wl[3]; const float* wr[3]; const float* bl[3];
    const float* g[3];  const float* be[3]; const float* rm[3]; const float* rv[3];
    for (int i = 0; i < 3; ++i) {
        wl[i] = (const float*)d_in[2 + 7 * i];
        wr[i] = (const float*)d_in[3 + 7 * i];
        bl[i] = (const float*)d_in[4 + 7 * i];
        g[i]  = (const float*)d_in[5 + 7 * i];
        be[i] = (const float*)d_in[6 + 7 * i];
        rm[i] = (const float*)d_in[7 + 7 * i];
        rv[i] = (const float*)d_in[8 + 7 * i];
    }
    const float* lin_w = (const float*)d_in[23];
    const float* lin_b = (const float*)d_in[24];
    float* out = (float*)d_out;

    // Workspace carve-up (~91 MB total).
    char* ws = (char*)d_ws;
    size_t off = 0;
    auto carve = [&](size_t bytes) -> void* {
        void* p = ws + off;
        off += (bytes + 255) & ~(size_t)255;
        return p;
    };
    int*    rowptr = (int*)carve((size_t)(N_NODES + 8) * sizeof(int));
    int*    eidx   = (int*)carve((size_t)N_EDGES * sizeof(int));
    uint*   scat   = (uint*)carve((size_t)N_EDGES * sizeof(uint));
    int*    ghist  = (int*)carve((size_t)(256 * K2CHUNK) * sizeof(int));
    int*    gbb    = (int*)carve((NBUCK + 4) * sizeof(int));
    ushort* tbuf   = (ushort*)carve((size_t)M_PAD * 256 * sizeof(ushort));
    ushort* h      = (ushort*)carve((size_t)M_PAD * HID * sizeof(ushort));
    ushort* Bt0    = (ushort*)carve(256 * IN_DIM * sizeof(ushort));
    ushort* Bt1    = (ushort*)carve(256 * HID * sizeof(ushort));
    ushort* Bt2    = (ushort*)carve(256 * HID * sizeof(ushort));
    float*  bnsc   = (float*)carve(3 * HID * sizeof(float));
    float*  bnsh   = (float*)carve(3 * HID * sizeof(float));
    (void)ws_size; (void)n_in; (void)in_sizes; (void)out_size;

    // CSR build (no memsets needed: all buffers fully written before read).
    hist_kernel<<<NBUCK, 256, 0, stream>>>(edst, ghist);
    scan_hist_kernel<<<1, 256, 0, stream>>>(ghist, gbb);
    scatter_kernel<<<NBUCK, 256, 0, stream>>>(esrc, edst, ghist, scat);
    bucket_csr_kernel<<<NBUCK, 256, 0, stream>>>(scat, gbb, rowptr, eidx);

    prep_weights_kernel<<<dim3((IN_DIM + 63) / 64, 256), 64, 0, stream>>>(wl[0], wr[0], Bt0, IN_DIM);
    prep_weights_kernel<<<dim3((HID + 63) / 64, 256), 64, 0, stream>>>(wl[1], wr[1], Bt1, HID);
    prep_weights_kernel<<<dim3((HID + 63) / 64, 256), 64, 0, stream>>>(wl[2], wr[2], Bt2, HID);
    bn_prep_kernel<<<1, HID, 0, stream>>>(bl[0], g[0], be[0], rm[0], rv[0], bnsc, bnsh);
    bn_prep_kernel<<<1, HID, 0, stream>>>(bl[1], g[1], be[1], rm[1], rv[1], bnsc + HID, bnsh + HID);
    bn_prep_kernel<<<1, HID, 0, stream>>>(bl[2], g[2], be[2], rm[2], rv[2], bnsc + 2 * HID, bnsh + 2 * HID);

    const int GEMM_GRID = M_PAD / 128;          // 782
    const int AGG_GRID = N_NODES / (4 * NPN);   // 6250

    gemm_kernel<IN_DIM, true><<<GEMM_GRID, 256, 0, stream>>>(x, Bt0, tbuf);
    agg_kernel<false><<<AGG_GRID, 256, 0, stream>>>(tbuf, rowptr, eidx, bnsc, bnsh,
                                                    nullptr, nullptr, h, nullptr);
    gemm_kernel<HID, false><<<GEMM_GRID, 256, 0, stream>>>(h, Bt1, tbuf);
    agg_kernel<false><<<AGG_GRID, 256, 0, stream>>>(tbuf, rowptr, eidx, bnsc + HID, bnsh + HID,
                                                    nullptr, nullptr, h, nullptr);
    gemm_kernel<HID, false><<<GEMM_GRID, 256, 0, stream>>>(h, Bt2, tbuf);
    agg_kernel<true><<<AGG_GRID, 256, 0, stream>>>(tbuf, rowptr, eidx, bnsc + 2 * HID, bnsh + 2 * HID,
                                                   lin_w, lin_b, nullptr, out);
}